// Round 18
// baseline (449.495 us; speedup 1.0000x reference)
//
#include <hip/hip_runtime.h>
#include <math.h>

#define BB 16
#define NN 4096
#define M_TOT (BB*NN)   // 65536 points
#define TBK 32
#define HBK 64

typedef __attribute__((ext_vector_type(8))) short s8v;   // 8 bf16 = 4 VGPRs
typedef __attribute__((ext_vector_type(4))) float f4v;

// exact tanh-GELU via sigmoid identity: 0.5x(1+tanh(z)) = x * sigmoid(2z)
__device__ __forceinline__ float gelu_t(float x){
    float u = 1.5957691216057308f * x * (1.0f + 0.044715f*x*x);
    return x / (1.0f + __expf(-u));
}

__device__ __forceinline__ unsigned short f2bf(float f){
    unsigned int u = __float_as_uint(f);
    u += 0x7fffu + ((u >> 16) & 1u);
    return (unsigned short)(u >> 16);
}

#define GLL(src, dst) __builtin_amdgcn_global_load_lds( \
    (const __attribute__((address_space(1))) void*)(src), \
    (__attribute__((address_space(3))) void*)(dst), 16, 0, 0)

// ---------------- chunked-staging conv device fn ----------------
template<int CIN, int COUT, int STRIDE, int CHUNK>
__device__ __forceinline__ void conv_dev2(
    const float* __restrict__ in, const float* __restrict__ w,
    const float* __restrict__ bias, float* __restrict__ out,
    int Hin, int Win, int Hout, int Wout, int bx, int by, int b, float* tile)
{
    constexpr int IW = 15*STRIDE + 3;
    constexpr int IH = IW;
    constexpr int PITCH = IW + 1;
    int tid = threadIdx.x;
    int tx = tid & 15, ty = tid >> 4;
    int wo = bx*16 + tx;
    int ho = by*16 + ty;
    int win0 = bx*16*STRIDE - 1;
    int hin0 = by*16*STRIDE - 1;
    bool valid = (wo < Wout) && (ho < Hout);

    float acc[COUT];
    #pragma unroll
    for (int co = 0; co < COUT; ++co) acc[co] = bias[co];

    const float* ib = in + (size_t)(b*CIN)*Hin*Win;
    for (int ci0 = 0; ci0 < CIN; ci0 += CHUNK) {
        __syncthreads();
        for (int idx = tid; idx < CHUNK*IH*IW; idx += 256) {
            int c = idx / (IH*IW), rem = idx - c*(IH*IW);
            int r = rem / IW, cc = rem - r*IW;
            int hi = hin0 + r, wi = win0 + cc;
            float v = 0.f;
            if ((unsigned)hi < (unsigned)Hin && (unsigned)wi < (unsigned)Win)
                v = ib[(size_t)(ci0 + c)*Hin*Win + hi*Win + wi];
            tile[c*IH*PITCH + r*PITCH + cc] = v;
        }
        __syncthreads();
        for (int ci = 0; ci < CHUNK; ++ci) {
            float vv[9];
            const float* tb = tile + ci*IH*PITCH;
            #pragma unroll
            for (int kh = 0; kh < 3; ++kh)
                #pragma unroll
                for (int kw = 0; kw < 3; ++kw)
                    vv[kh*3+kw] = tb[(ty*STRIDE + kh)*PITCH + tx*STRIDE + kw];
            const float* wc = w + (ci0 + ci)*9;
            #pragma unroll
            for (int co = 0; co < COUT; ++co) {
                const float* wp = wc + co*CIN*9;
                #pragma unroll
                for (int k = 0; k < 9; ++k)
                    acc[co] = fmaf(vv[k], wp[k], acc[co]);
            }
        }
    }
    if (valid) {
        size_t obase = ((size_t)b*COUT)*Hout*Wout + (size_t)ho*Wout + wo;
        #pragma unroll
        for (int co = 0; co < COUT; ++co)
            out[obase + (size_t)co*Hout*Wout] = gelu_t(acc[co]);
    }
}

// ================= K1: conv_dual (784 blocks) + mlpA (1024 blocks), concurrent =================
__global__ __launch_bounds__(256) void k1_k(
    const float* __restrict__ images,
    const float* __restrict__ pw1, const float* __restrict__ pb1,
    const float* __restrict__ gw1, const float* __restrict__ gb1,
    float* __restrict__ f1, float* __restrict__ g1,
    const float* __restrict__ points,
    const unsigned short* __restrict__ W1, const float* __restrict__ b1,
    const unsigned short* __restrict__ W2, const float* __restrict__ b2,
    unsigned short* __restrict__ C)
{
    __shared__ char smem[32768];
    int bid = blockIdx.x;
    int tid = threadIdx.x;
    if (bid < 784) {
        // ---- conv_dual: plane conv1 (16ch) + global conv1 (4ch), all 3 ci staged once ----
        float* tile = (float*)smem;   // 3*33*34 floats = 13.5 KB
        const int Hin = 224, Win = 224, Hout = 112, Wout = 112;
        int b = bid / 49, rem = bid - b*49;
        int by = rem / 7, bx = rem - by*7;
        int tx = tid & 15, ty = tid >> 4;
        int wo = bx*16 + tx;
        int ho = by*16 + ty;
        int win0 = bx*32 - 1;
        int hin0 = by*32 - 1;

        const float* ib = images + (size_t)(b*3)*Hin*Win;
        for (int idx = tid; idx < 3*1089; idx += 256) {
            int c = idx / 1089, r2 = idx - c*1089;
            int r = r2 / 33, cc = r2 - r*33;
            int hi = hin0 + r, wi = win0 + cc;
            float v = 0.f;
            if ((unsigned)hi < (unsigned)Hin && (unsigned)wi < (unsigned)Win)
                v = ib[(size_t)c*Hin*Win + hi*Win + wi];
            tile[c*33*34 + r*34 + cc] = v;
        }
        __syncthreads();

        float accA[16], accB[4];
        #pragma unroll
        for (int co = 0; co < 16; ++co) accA[co] = pb1[co];
        #pragma unroll
        for (int co = 0; co < 4; ++co) accB[co] = gb1[co];

        #pragma unroll
        for (int ci = 0; ci < 3; ++ci) {
            float vv[9];
            const float* tb = tile + ci*33*34;
            #pragma unroll
            for (int kh = 0; kh < 3; ++kh)
                #pragma unroll
                for (int kw = 0; kw < 3; ++kw)
                    vv[kh*3+kw] = tb[(ty*2 + kh)*34 + tx*2 + kw];
            #pragma unroll
            for (int co = 0; co < 16; ++co) {
                const float* wp = pw1 + co*27 + ci*9;
                #pragma unroll
                for (int k = 0; k < 9; ++k) accA[co] = fmaf(vv[k], wp[k], accA[co]);
            }
            #pragma unroll
            for (int co = 0; co < 4; ++co) {
                const float* wp = gw1 + co*27 + ci*9;
                #pragma unroll
                for (int k = 0; k < 9; ++k) accB[co] = fmaf(vv[k], wp[k], accB[co]);
            }
        }
        size_t px = (size_t)ho*Wout + wo;
        #pragma unroll
        for (int co = 0; co < 16; ++co)
            f1[((size_t)(b*16 + co))*Hout*Wout + px] = gelu_t(accA[co]);
        #pragma unroll
        for (int co = 0; co < 4; ++co)
            g1[((size_t)(b*4 + co))*Hout*Wout + px] = gelu_t(accB[co]);
    } else {
        // ---- mlpA: embed + mlp1 + mlp2 -> fused cols 0..255, M-strip 64 ----
        unsigned short* Hd = (unsigned short*)smem;   // 64x256 bf16 = 32 KB
        int wv = tid >> 6, lane = tid & 63;
        int q = lane >> 4, lr = lane & 15;
        int nq = wv * 64;
        size_t m0 = (size_t)(bid - 784) * 64;

        f4v acc1[4][4];
        #pragma unroll
        for (int i = 0; i < 4; ++i)
            #pragma unroll
            for (int j = 0; j < 4; ++j) acc1[i][j] = (f4v){0.f,0.f,0.f,0.f};

        #pragma unroll
        for (int kb = 0; kb < 2; ++kb) {
            int seg = kb*4 + q;
            s8v a[4], b[4];
            #pragma unroll
            for (int t = 0; t < 4; ++t) {
                size_t m = m0 + t*16 + lr;
                float px = points[m*2], py = points[m*2+1];
                union { s8v v; unsigned short u[8]; } pk;
                #pragma unroll
                for (int j = 0; j < 8; ++j) {
                    int k = seg*8 + j;
                    unsigned short val = 0;
                    if (k < 48) {
                        int i2 = k >> 2, rr = k & 3;
                        float f = (float)(1 << i2);
                        float p = (rr & 1) ? py : px;
                        float s = f * p;
                        val = f2bf((rr < 2) ? __sinf(s) : __cosf(s));
                    }
                    pk.u[j] = val;
                }
                a[t] = pk.v;
            }
            #pragma unroll
            for (int t = 0; t < 4; ++t) {
                int n = nq + t*16 + lr;
                b[t] = *(const s8v*)(W1 + n*64 + seg*8);
            }
            #pragma unroll
            for (int mt = 0; mt < 4; ++mt)
                #pragma unroll
                for (int nt = 0; nt < 4; ++nt)
                    acc1[mt][nt] = __builtin_amdgcn_mfma_f32_16x16x32_bf16(a[mt], b[nt], acc1[mt][nt], 0, 0, 0);
        }
        {
            float b1v[4];
            #pragma unroll
            for (int nt = 0; nt < 4; ++nt) b1v[nt] = b1[nq + nt*16 + lr];
            #pragma unroll
            for (int mt = 0; mt < 4; ++mt)
                #pragma unroll
                for (int r4 = 0; r4 < 4; ++r4) {
                    int row = mt*16 + q*4 + r4;
                    #pragma unroll
                    for (int nt = 0; nt < 4; ++nt) {
                        int col = nq + nt*16 + lr;
                        float v = gelu_t(acc1[mt][nt][r4] + b1v[nt]);
                        int p = (col >> 3) ^ (row & 7);
                        Hd[(row*32 + p)*8 + (col & 7)] = f2bf(v);
                    }
                }
        }
        __syncthreads();

        f4v acc2[4][4];
        #pragma unroll
        for (int i = 0; i < 4; ++i)
            #pragma unroll
            for (int j = 0; j < 4; ++j) acc2[i][j] = (f4v){0.f,0.f,0.f,0.f};

        #pragma unroll 2
        for (int kt = 0; kt < 8; ++kt) {
            s8v a[4], b[4];
            #pragma unroll
            for (int t = 0; t < 4; ++t) {
                int n = nq + t*16 + lr;
                b[t] = *(const s8v*)(W2 + (size_t)n*256 + kt*32 + q*8);
            }
            #pragma unroll
            for (int t = 0; t < 4; ++t) {
                int row = t*16 + lr;
                int p = (kt*4 + q) ^ (row & 7);
                a[t] = *(const s8v*)(Hd + (row*32 + p)*8);
            }
            #pragma unroll
            for (int mt = 0; mt < 4; ++mt)
                #pragma unroll
                for (int nt = 0; nt < 4; ++nt)
                    acc2[mt][nt] = __builtin_amdgcn_mfma_f32_16x16x32_bf16(a[mt], b[nt], acc2[mt][nt], 0, 0, 0);
        }
        float b2v[4];
        #pragma unroll
        for (int nt = 0; nt < 4; ++nt) b2v[nt] = b2[nq + nt*16 + lr];
        #pragma unroll
        for (int mt = 0; mt < 4; ++mt)
            #pragma unroll
            for (int r4 = 0; r4 < 4; ++r4) {
                size_t m = m0 + mt*16 + q*4 + r4;
                #pragma unroll
                for (int nt = 0; nt < 4; ++nt) {
                    int n = nq + nt*16 + lr;
                    C[m*512 + n] = f2bf(acc2[mt][nt][r4] + b2v[nt]);
                }
            }
    }
}

// ---------------- layer-2 convs: plane p2 (16->32, split co 2x16) + global g2 (4->8) ----------------
__global__ __launch_bounds__(256) void conv_pg2_k(
    const float* __restrict__ f1, const float* __restrict__ pw2, const float* __restrict__ pb2, float* __restrict__ f2,
    const float* __restrict__ g1, const float* __restrict__ gw2, const float* __restrict__ gb2, float* __restrict__ g2)
{
    __shared__ float tile[8*33*34];   // 35.9 KB
    int z = blockIdx.z;
    if (z < 32) {
        int b = z >> 1, half = z & 1;
        conv_dev2<16,16,2,8>(f1 + (size_t)b*16*12544, pw2 + half*2304, pb2 + half*16,
                             f2 + ((size_t)(b*32 + half*16))*3136,
                             112,112, 56,56, blockIdx.x, blockIdx.y, 0, tile);
    } else {
        conv_dev2<4,8,2,4>(g1, gw2, gb2, g2, 112,112, 56,56, blockIdx.x, blockIdx.y, z-32, tile);
    }
}

// ---------------- layer-3: plane p3 DIRECT (32->4, NHWC out) + global g3 (8->16, LDS) ----------------
__global__ __launch_bounds__(256) void conv_pg3_k(
    const float* __restrict__ f2, const float* __restrict__ pw3, const float* __restrict__ pb3, float4* __restrict__ fmap4,
    const float* __restrict__ g2, const float* __restrict__ gw3, const float* __restrict__ gb3, float* __restrict__ g3)
{
    __shared__ float tile[8*33*34];
    int z = blockIdx.z;
    if (z < 16) {
        int b = z;
        int idx = blockIdx.x*256 + threadIdx.x;
        if (idx >= 3136) return;
        int ho = idx / 56, wo = idx - ho*56;
        const float* ib = f2 + (size_t)b*32*3136;
        float acc[4];
        #pragma unroll
        for (int co = 0; co < 4; ++co) acc[co] = pb3[co];
        for (int ci = 0; ci < 32; ++ci) {
            const float* ic = ib + (size_t)ci*3136;
            #pragma unroll
            for (int kh = 0; kh < 3; ++kh) {
                int hi = ho - 1 + kh;
                if ((unsigned)hi >= 56u) continue;
                #pragma unroll
                for (int kw = 0; kw < 3; ++kw) {
                    int wi = wo - 1 + kw;
                    if ((unsigned)wi >= 56u) continue;
                    float v = ic[hi*56 + wi];
                    int wofs = ci*9 + kh*3 + kw;
                    #pragma unroll
                    for (int co = 0; co < 4; ++co)
                        acc[co] = fmaf(v, pw3[co*288 + wofs], acc[co]);
                }
            }
        }
        float4 o;
        o.x = gelu_t(acc[0]); o.y = gelu_t(acc[1]);
        o.z = gelu_t(acc[2]); o.w = gelu_t(acc[3]);
        fmap4[(size_t)b*3136 + idx] = o;
    } else {
        if (blockIdx.x >= 4) return;
        int bx = blockIdx.x & 1, by = blockIdx.x >> 1;
        conv_dev2<8,16,2,8>(g2, gw3, gb3, g3, 56,56, 28,28, bx, by, z-16, tile);
    }
}

// ================= K4: g4 (392 blocks) + fill_patch (16384 blocks) =================
__global__ __launch_bounds__(256) void k4_k(
    const float* __restrict__ g3, const float* __restrict__ w4,
    const float* __restrict__ b4, float* __restrict__ g4o,
    const float4* __restrict__ fmap4, const float* __restrict__ points,
    unsigned short* __restrict__ C)
{
    int bid = blockIdx.x;
    int tid = threadIdx.x;
    if (bid < 392) {
        int idx = bid*256 + tid;
        int co = idx & 31;
        int t = idx >> 5;
        int b = t / 196, px = t - b*196;
        int ho = px / 14, wo = px - ho*14;
        const float* src = g3 + (size_t)b*16*784;
        const float* wp = w4 + co*144;
        float acc = b4[co];
        for (int ci = 0; ci < 16; ++ci) {
            #pragma unroll
            for (int kh = 0; kh < 3; ++kh) {
                int hi = ho*2 - 1 + kh;
                if ((unsigned)hi >= 28u) continue;
                #pragma unroll
                for (int kw = 0; kw < 3; ++kw) {
                    int wi = wo*2 - 1 + kw;
                    if ((unsigned)wi >= 28u) continue;
                    acc = fmaf(src[ci*784 + hi*28 + wi], wp[ci*9 + kh*3 + kw], acc);
                }
            }
        }
        g4o[(size_t)b*6272 + px*32 + co] = gelu_t(acc);
    } else {
        int task = (bid - 392)*256 + tid;     // M*64 tasks
        int ml = task >> 6, ij = task & 63;
        size_t m = (size_t)ml;
        int i = ij >> 3, j = ij & 7;
        int b = (int)(m >> 12);
        float px = points[m*2], py = points[m*2+1];
        float cx = px*2.f - 1.f, cy = py*2.f - 1.f;
        const float step = 2.0f/55.0f;
        float gx = cx + ((float)i - 3.5f)*step;
        float gy = cy + ((float)j - 3.5f)*step;
        float ix = (gx + 1.f)*0.5f*55.f;
        float iy = (gy + 1.f)*0.5f*55.f;
        float x0f = floorf(ix), y0f = floorf(iy);
        int x0 = (int)x0f, y0 = (int)y0f;
        int x1 = x0 + 1,  y1 = y0 + 1;
        float wx1 = ix - x0f, wx0 = 1.f - wx1;
        float wy1 = iy - y0f, wy0 = 1.f - wy1;
        float v00 = ((x0>=0)&&(x0<56)&&(y0>=0)&&(y0<56)) ? 1.f : 0.f;
        float v10 = ((x1>=0)&&(x1<56)&&(y0>=0)&&(y0<56)) ? 1.f : 0.f;
        float v01 = ((x0>=0)&&(x0<56)&&(y1>=0)&&(y1<56)) ? 1.f : 0.f;
        float v11 = ((x1>=0)&&(x1<56)&&(y1>=0)&&(y1<56)) ? 1.f : 0.f;
        float w00 = wx0*wy0*v00, w10 = wx1*wy0*v10, w01 = wx0*wy1*v01, w11 = wx1*wy1*v11;
        int cx0 = min(max(x0,0),55), cx1 = min(max(x1,0),55);
        int cy0 = min(max(y0,0),55), cy1 = min(max(y1,0),55);
        const float4* fb = fmap4 + (size_t)b*3136;
        float4 f00 = fb[cy0*56 + cx0], f10 = fb[cy0*56 + cx1];
        float4 f01 = fb[cy1*56 + cx0], f11 = fb[cy1*56 + cx1];
        float4 v;
        v.x = w00*f00.x + w10*f10.x + w01*f01.x + w11*f11.x;
        v.y = w00*f00.y + w10*f10.y + w01*f01.y + w11*f11.y;
        v.z = w00*f00.z + w10*f10.z + w01*f01.z + w11*f11.z;
        v.w = w00*f00.w + w10*f10.w + w01*f01.w + w11*f11.w;
        C[m*512 + 256 +   0 + ij] = f2bf(v.x);
        C[m*512 + 256 +  64 + ij] = f2bf(v.y);
        C[m*512 + 256 + 128 + ij] = f2bf(v.z);
        C[m*512 + 256 + 192 + ij] = f2bf(v.w);
    }
}

// ---------------- g5 + avgpool: 32->64, 14->7, s2; atomic pool into gc ----------------
__global__ __launch_bounds__(256) void g5_k(
    const float* __restrict__ g4o, const float* __restrict__ w5,
    const float* __restrict__ b5, float* __restrict__ gc)
{
    int idx = blockIdx.x*256 + threadIdx.x;      // 196 blocks, exact
    int co = idx & 63;
    int t = idx >> 6;
    int b = t / 49, px = t - b*49;
    int ho = px / 7, wo = px - ho*7;
    const float* src = g4o + (size_t)b*6272;
    const float* wp = w5 + co*288;
    float acc = b5[co];
    for (int ci = 0; ci < 32; ++ci) {
        #pragma unroll
        for (int kh = 0; kh < 3; ++kh) {
            int hi = ho*2 - 1 + kh;
            if ((unsigned)hi >= 14u) continue;
            #pragma unroll
            for (int kw = 0; kw < 3; ++kw) {
                int wi = wo*2 - 1 + kw;
                if ((unsigned)wi >= 14u) continue;
                acc = fmaf(src[(hi*14 + wi)*32 + ci], wp[ci*9 + kh*3 + kw], acc);
            }
        }
    }
    atomicAdd(&gc[b*64 + co], gelu_t(acc) * (1.0f/49.0f));
}

// ---------------- hgc: effective head bias  hgc[b][n] = hb1[n] + sum_c gc[b,c]*hw1[n,512+c] ----------------
__global__ __launch_bounds__(256) void hgc_k(
    const float* __restrict__ gc, const float* __restrict__ hw1,
    const float* __restrict__ hb1, float* __restrict__ hgc)
{
    int idx = blockIdx.x*256 + threadIdx.x;   // 32 blocks = 8192
    int b = idx >> 9, n = idx & 511;
    const float* g = gc + b*64;
    const float* w = hw1 + (size_t)n*576 + 512;
    float s = hb1[n];
    #pragma unroll
    for (int c = 0; c < 64; ++c) s = fmaf(g[c], w[c], s);
    hgc[idx] = s;
}

// ---------------- weight conversions + out init + gc zero ----------------
__global__ void cvtall_k(const float* __restrict__ lw1, const float* __restrict__ lw2,
                         const float* __restrict__ hw1, unsigned short* __restrict__ blw1,
                         unsigned short* __restrict__ blw2, unsigned short* __restrict__ bhw1,
                         float* __restrict__ out, const float* __restrict__ b2,
                         float* __restrict__ gc){
    int i = blockIdx.x*blockDim.x + threadIdx.x;
    if (i < M_TOT) out[i] = b2[0];
    if (i < 1024) gc[i] = 0.f;
    if (i < 256*64) {
        int r = i >> 6, c = i & 63;
        blw1[i] = (c < 48) ? f2bf(lw1[r*48 + c]) : 0;
        return;
    }
    int j = i - 256*64;
    if (j < 256*256) { blw2[j] = f2bf(lw2[j]); return; }
    j -= 256*256;
    if (j < 512*576) bhw1[j] = f2bf(hw1[j]);
}

// ================= head: 256 thr, M-strip 64, N-split 2, BK=64, K=512, bias from hgc =================
__global__ __launch_bounds__(256, 3) void gemm_hd_k(
    const unsigned short* __restrict__ A,
    const unsigned short* __restrict__ W,
    const float* __restrict__ hgc, const float* __restrict__ w2,
    float* __restrict__ out)
{
    __shared__ unsigned short As[64*HBK];    // 8 KB
    __shared__ unsigned short Bs[256*HBK];   // 32 KB
    __shared__ float red[4*64];
    int tid = threadIdx.x;
    int wv = tid >> 6, lane = tid & 63;
    int q = lane >> 4, lr = lane & 15;
    int nq = wv * 64;
    size_t m0 = (size_t)blockIdx.x * 64;
    int nbase = blockIdx.y * 256;
    int bimg = (int)(m0 >> 12);              // image index, uniform per block

    const unsigned short* srcA[2]; unsigned short* dstA[2];
    #pragma unroll
    for (int r = 0; r < 2; ++r) {
        int f = r*256 + tid;
        int row = f >> 3, sl = (f & 7) ^ (row & 7);
        srcA[r] = A + (m0 + row)*512 + sl*8;
        dstA[r] = As + f*8;
    }
    const unsigned short* srcB[8]; unsigned short* dstB[8];
    #pragma unroll
    for (int r = 0; r < 8; ++r) {
        int f = r*256 + tid;
        int row = f >> 3, sl = (f & 7) ^ (row & 7);
        srcB[r] = W + (size_t)(nbase + row)*576 + sl*8;
        dstB[r] = Bs + f*8;
    }

    f4v acc[4][4];
    #pragma unroll
    for (int i = 0; i < 4; ++i)
        #pragma unroll
        for (int j = 0; j < 4; ++j) acc[i][j] = (f4v){0.f,0.f,0.f,0.f};

    for (int k0 = 0; k0 < 512; k0 += HBK) {
        #pragma unroll
        for (int r = 0; r < 2; ++r) { GLL(srcA[r], dstA[r]); srcA[r] += HBK; }
        #pragma unroll
        for (int r = 0; r < 8; ++r) { GLL(srcB[r], dstB[r]); srcB[r] += HBK; }
        __syncthreads();
        #pragma unroll
        for (int kk = 0; kk < 2; ++kk) {
            s8v a[4], b[4];
            #pragma unroll
            for (int t = 0; t < 4; ++t) {
                int row = t*16 + lr;
                int ph = (kk*4 + q) ^ (row & 7);
                a[t] = *(const s8v*)(As + (row*8 + ph)*8);
            }
            #pragma unroll
            for (int t = 0; t < 4; ++t) {
                int row = nq + t*16 + lr;
                int ph = (kk*4 + q) ^ (row & 7);
                b[t] = *(const s8v*)(Bs + (row*8 + ph)*8);
            }
            #pragma unroll
            for (int mt = 0; mt < 4; ++mt)
                #pragma unroll
                for (int nt = 0; nt < 4; ++nt)
                    acc[mt][nt] = __builtin_amdgcn_mfma_f32_16x16x32_bf16(a[mt], b[nt], acc[mt][nt], 0, 0, 0);
        }
        __syncthreads();
    }
    float bv[4], w2v[4];
    #pragma unroll
    for (int nt = 0; nt < 4; ++nt) {
        int n = nbase + nq + nt*16 + lr;
        bv[nt] = hgc[bimg*512 + n];
        w2v[nt] = w2[n];
    }
    #pragma unroll
    for (int mt = 0; mt < 4; ++mt)
        #pragma unroll
        for (int r4 = 0; r4 < 4; ++r4) {
            int ml = mt*16 + q*4 + r4;
            float s = 0.f;
            #pragma unroll
            for (int nt = 0; nt < 4; ++nt)
                s += gelu_t(acc[mt][nt][r4] + bv[nt]) * w2v[nt];
            #pragma unroll
            for (int off = 8; off > 0; off >>= 1) s += __shfl_down(s, off, 16);
            if (lr == 0) red[wv*64 + ml] = s;
        }
    __syncthreads();
    if (tid < 64) {
        float t = red[tid] + red[64 + tid] + red[128 + tid] + red[192 + tid];
        atomicAdd(&out[m0 + tid], t);
    }
}

extern "C" void kernel_launch(void* const* d_in, const int* in_sizes, int n_in,
                              void* d_out, int out_size, void* d_ws, size_t ws_size,
                              hipStream_t stream) {
    const float* points = (const float*)d_in[0];
    const float* images = (const float*)d_in[1];
    const float* pw1 = (const float*)d_in[2];  const float* pb1 = (const float*)d_in[3];
    const float* pw2 = (const float*)d_in[4];  const float* pb2 = (const float*)d_in[5];
    const float* pw3 = (const float*)d_in[6];  const float* pb3 = (const float*)d_in[7];
    const float* gw1 = (const float*)d_in[8];  const float* gb1 = (const float*)d_in[9];
    const float* gw2 = (const float*)d_in[10]; const float* gb2 = (const float*)d_in[11];
    const float* gw3 = (const float*)d_in[12]; const float* gb3 = (const float*)d_in[13];
    const float* gw4 = (const float*)d_in[14]; const float* gb4 = (const float*)d_in[15];
    const float* gw5 = (const float*)d_in[16]; const float* gb5 = (const float*)d_in[17];
    const float* lw1 = (const float*)d_in[18]; const float* lb1 = (const float*)d_in[19];
    const float* lw2 = (const float*)d_in[20]; const float* lb2 = (const float*)d_in[21];
    const float* hw1 = (const float*)d_in[22]; const float* hb1 = (const float*)d_in[23];
    const float* hw2 = (const float*)d_in[24]; const float* hb2 = (const float*)d_in[25];
    float* out = (float*)d_out;

    // ---- workspace layout ----
    char* base = (char*)d_ws;
    unsigned short* fused_b = (unsigned short*)base;                       // M*512 bf16 = 64 MB
    float* conv = (float*)(fused_b + (size_t)M_TOT*512);                   // conv temps (concurrent w/ fused)
    float* f1 = conv;                                                      // 3,211,264
    float* f2 = f1 + (size_t)16*16*112*112;                                // 1,605,632
    float* g1 = f2 + (size_t)16*32*56*56;                                  //   802,816
    float* g2 = g1 + (size_t)16*4*112*112;                                 //   401,408
    float* g3 = g2 + (size_t)16*8*56*56;                                   //   200,704
    float* g4 = g3 + (size_t)16*16*28*28;                                  //   100,352 (NHWC)
    float4* fmap4 = (float4*)(g4 + (size_t)16*32*14*14);                   // 16*3136 float4
    float* gc   = (float*)(fmap4 + (size_t)16*3136);                       // 1024
    float* hgc  = gc + 1024;                                               // 16*512
    unsigned short* blw1 = (unsigned short*)(hgc + 16*512);                // 256*64
    unsigned short* blw2 = blw1 + 256*64;                                  // 256*256
    unsigned short* bhw1 = blw2 + 256*256;                                 // 512*576

    cvtall_k<<<1472, 256, 0, stream>>>(lw1, lw2, hw1, blw1, blw2, bhw1, out, hb2, gc);
    // K1: conv1(dual) + mlp(embed+mlp1+mlp2 -> fused cols 0..255), concurrent
    k1_k<<<784 + 1024, 256, 0, stream>>>(images, pw1, pb1, gw1, gb1, f1, g1,
                                         points, blw1, lb1, blw2, lb2, fused_b);
    conv_pg2_k<<<dim3(4,4,48), 256, 0, stream>>>(f1, pw2, pb2, f2, g1, gw2, gb2, g2);
    conv_pg3_k<<<dim3(13,1,32), 256, 0, stream>>>(f2, pw3, pb3, fmap4, g2, gw3, gb3, g3);
    // K4: g4 + patch fill (both depend only on pg3)
    k4_k<<<392 + 16384, 256, 0, stream>>>(g3, gw4, gb4, g4, fmap4, points, fused_b);
    g5_k<<<196, 256, 0, stream>>>(g4, gw5, gb5, gc);   // includes avgpool via atomics
    hgc_k<<<32, 256, 0, stream>>>(gc, hw1, hb1, hgc);
    // head: K=512, bias_eff = hb1 + gc-contribution (fp32-exact)
    gemm_hd_k<<<dim3(M_TOT/64, 2), 256, 0, stream>>>(fused_b, bhw1, hgc, hw2, out);
}

// Round 19
// 427.737 us; speedup vs baseline: 1.0509x; 1.0509x over previous
//
#include <hip/hip_runtime.h>
#include <math.h>

#define BB 16
#define NN 4096
#define M_TOT (BB*NN)   // 65536 points
#define TBK 32
#define HBK 64

typedef __attribute__((ext_vector_type(8))) short s8v;   // 8 bf16 = 4 VGPRs
typedef __attribute__((ext_vector_type(4))) float f4v;

// exact tanh-GELU via sigmoid identity: 0.5x(1+tanh(z)) = x * sigmoid(2z)
__device__ __forceinline__ float gelu_t(float x){
    float u = 1.5957691216057308f * x * (1.0f + 0.044715f*x*x);
    return x / (1.0f + __expf(-u));
}

__device__ __forceinline__ unsigned short f2bf(float f){
    unsigned int u = __float_as_uint(f);
    u += 0x7fffu + ((u >> 16) & 1u);
    return (unsigned short)(u >> 16);
}

#define GLL(src, dst) __builtin_amdgcn_global_load_lds( \
    (const __attribute__((address_space(1))) void*)(src), \
    (__attribute__((address_space(3))) void*)(dst), 16, 0, 0)

// ---------------- chunked-staging conv device fn: CHUNK channels per barrier ----------------
template<int CIN, int COUT, int STRIDE, int CHUNK>
__device__ __forceinline__ void conv_dev2(
    const float* __restrict__ in, const float* __restrict__ w,
    const float* __restrict__ bias, float* __restrict__ out,
    int Hin, int Win, int Hout, int Wout, int bx, int by, int b, float* tile)
{
    constexpr int IW = 15*STRIDE + 3;
    constexpr int IH = IW;
    constexpr int PITCH = IW + 1;
    int tid = threadIdx.x;
    int tx = tid & 15, ty = tid >> 4;
    int wo = bx*16 + tx;
    int ho = by*16 + ty;
    int win0 = bx*16*STRIDE - 1;
    int hin0 = by*16*STRIDE - 1;
    bool valid = (wo < Wout) && (ho < Hout);

    float acc[COUT];
    #pragma unroll
    for (int co = 0; co < COUT; ++co) acc[co] = bias[co];

    const float* ib = in + (size_t)(b*CIN)*Hin*Win;
    for (int ci0 = 0; ci0 < CIN; ci0 += CHUNK) {
        __syncthreads();
        for (int idx = tid; idx < CHUNK*IH*IW; idx += 256) {
            int c = idx / (IH*IW), rem = idx - c*(IH*IW);
            int r = rem / IW, cc = rem - r*IW;
            int hi = hin0 + r, wi = win0 + cc;
            float v = 0.f;
            if ((unsigned)hi < (unsigned)Hin && (unsigned)wi < (unsigned)Win)
                v = ib[(size_t)(ci0 + c)*Hin*Win + hi*Win + wi];
            tile[c*IH*PITCH + r*PITCH + cc] = v;
        }
        __syncthreads();
        for (int ci = 0; ci < CHUNK; ++ci) {
            float vv[9];
            const float* tb = tile + ci*IH*PITCH;
            #pragma unroll
            for (int kh = 0; kh < 3; ++kh)
                #pragma unroll
                for (int kw = 0; kw < 3; ++kw)
                    vv[kh*3+kw] = tb[(ty*STRIDE + kh)*PITCH + tx*STRIDE + kw];
            const float* wc = w + (ci0 + ci)*9;
            #pragma unroll
            for (int co = 0; co < COUT; ++co) {
                const float* wp = wc + co*CIN*9;
                #pragma unroll
                for (int k = 0; k < 9; ++k)
                    acc[co] = fmaf(vv[k], wp[k], acc[co]);
            }
        }
    }
    if (valid) {
        size_t obase = ((size_t)b*COUT)*Hout*Wout + (size_t)ho*Wout + wo;
        #pragma unroll
        for (int co = 0; co < COUT; ++co)
            out[obase + (size_t)co*Hout*Wout] = gelu_t(acc[co]);
    }
}

// ---------------- dual conv1: plane (16ch) + global (4ch), all 3 ci staged once ----------------
__global__ __launch_bounds__(256) void conv_dual_k(
    const float* __restrict__ in,
    const float* __restrict__ wA, const float* __restrict__ bA,
    const float* __restrict__ wB, const float* __restrict__ bB,
    float* __restrict__ outA, float* __restrict__ outB)
{
    __shared__ float tile[3*33*34];   // 13.5 KB
    const int Hin = 224, Win = 224, Hout = 112, Wout = 112;
    int tid = threadIdx.x;
    int tx = tid & 15, ty = tid >> 4;
    int b = blockIdx.z;
    int wo = blockIdx.x*16 + tx;
    int ho = blockIdx.y*16 + ty;
    int win0 = blockIdx.x*32 - 1;
    int hin0 = blockIdx.y*32 - 1;

    const float* ib = in + (size_t)(b*3)*Hin*Win;
    for (int idx = tid; idx < 3*1089; idx += 256) {
        int c = idx / 1089, rem = idx - c*1089;
        int r = rem / 33, cc = rem - r*33;
        int hi = hin0 + r, wi = win0 + cc;
        float v = 0.f;
        if ((unsigned)hi < (unsigned)Hin && (unsigned)wi < (unsigned)Win)
            v = ib[(size_t)c*Hin*Win + hi*Win + wi];
        tile[c*33*34 + r*34 + cc] = v;
    }
    __syncthreads();

    float accA[16], accB[4];
    #pragma unroll
    for (int co = 0; co < 16; ++co) accA[co] = bA[co];
    #pragma unroll
    for (int co = 0; co < 4; ++co) accB[co] = bB[co];

    #pragma unroll
    for (int ci = 0; ci < 3; ++ci) {
        float vv[9];
        const float* tb = tile + ci*33*34;
        #pragma unroll
        for (int kh = 0; kh < 3; ++kh)
            #pragma unroll
            for (int kw = 0; kw < 3; ++kw)
                vv[kh*3+kw] = tb[(ty*2 + kh)*34 + tx*2 + kw];
        #pragma unroll
        for (int co = 0; co < 16; ++co) {
            const float* wp = wA + co*27 + ci*9;
            #pragma unroll
            for (int k = 0; k < 9; ++k) accA[co] = fmaf(vv[k], wp[k], accA[co]);
        }
        #pragma unroll
        for (int co = 0; co < 4; ++co) {
            const float* wp = wB + co*27 + ci*9;
            #pragma unroll
            for (int k = 0; k < 9; ++k) accB[co] = fmaf(vv[k], wp[k], accB[co]);
        }
    }
    size_t px = (size_t)ho*Wout + wo;
    #pragma unroll
    for (int co = 0; co < 16; ++co)
        outA[((size_t)(b*16 + co))*Hout*Wout + px] = gelu_t(accA[co]);
    #pragma unroll
    for (int co = 0; co < 4; ++co)
        outB[((size_t)(b*4 + co))*Hout*Wout + px] = gelu_t(accB[co]);
}

// ---------------- layer-2 convs: plane p2 (16->32, split co 2x16) + global g2 (4->8) ----------------
__global__ __launch_bounds__(256) void conv_pg2_k(
    const float* __restrict__ f1, const float* __restrict__ pw2, const float* __restrict__ pb2, float* __restrict__ f2,
    const float* __restrict__ g1, const float* __restrict__ gw2, const float* __restrict__ gb2, float* __restrict__ g2)
{
    __shared__ float tile[8*33*34];   // 35.9 KB
    int z = blockIdx.z;
    if (z < 32) {
        int b = z >> 1, half = z & 1;
        conv_dev2<16,16,2,8>(f1 + (size_t)b*16*12544, pw2 + half*2304, pb2 + half*16,
                             f2 + ((size_t)(b*32 + half*16))*3136,
                             112,112, 56,56, blockIdx.x, blockIdx.y, 0, tile);
    } else {
        conv_dev2<4,8,2,4>(g1, gw2, gb2, g2, 112,112, 56,56, blockIdx.x, blockIdx.y, z-32, tile);
    }
}

// ---------------- layer-3: plane p3 DIRECT (32->4, NHWC out) + global g3 (8->16, LDS) ----------------
__global__ __launch_bounds__(256) void conv_pg3_k(
    const float* __restrict__ f2, const float* __restrict__ pw3, const float* __restrict__ pb3, float4* __restrict__ fmap4,
    const float* __restrict__ g2, const float* __restrict__ gw3, const float* __restrict__ gb3, float* __restrict__ g3)
{
    __shared__ float tile[8*33*34];
    int z = blockIdx.z;
    if (z < 16) {
        int b = z;
        int idx = blockIdx.x*256 + threadIdx.x;
        if (idx >= 3136) return;
        int ho = idx / 56, wo = idx - ho*56;
        const float* ib = f2 + (size_t)b*32*3136;
        float acc[4];
        #pragma unroll
        for (int co = 0; co < 4; ++co) acc[co] = pb3[co];
        for (int ci = 0; ci < 32; ++ci) {
            const float* ic = ib + (size_t)ci*3136;
            #pragma unroll
            for (int kh = 0; kh < 3; ++kh) {
                int hi = ho - 1 + kh;
                if ((unsigned)hi >= 56u) continue;
                #pragma unroll
                for (int kw = 0; kw < 3; ++kw) {
                    int wi = wo - 1 + kw;
                    if ((unsigned)wi >= 56u) continue;
                    float v = ic[hi*56 + wi];
                    int wofs = ci*9 + kh*3 + kw;
                    #pragma unroll
                    for (int co = 0; co < 4; ++co)
                        acc[co] = fmaf(v, pw3[co*288 + wofs], acc[co]);
                }
            }
        }
        float4 o;
        o.x = gelu_t(acc[0]); o.y = gelu_t(acc[1]);
        o.z = gelu_t(acc[2]); o.w = gelu_t(acc[3]);
        fmap4[(size_t)b*3136 + idx] = o;
    } else {
        if (blockIdx.x >= 4) return;
        int bx = blockIdx.x & 1, by = blockIdx.x >> 1;
        conv_dev2<8,16,2,8>(g2, gw3, gb3, g3, 56,56, 28,28, bx, by, z-16, tile);
    }
}

// ---------------- g4: 16->32, 28->14, s2. Thread per output; NHWC out ----------------
__global__ __launch_bounds__(256) void g4_k(
    const float* __restrict__ g3, const float* __restrict__ w4,
    const float* __restrict__ b4, float* __restrict__ g4o)
{
    int idx = blockIdx.x*256 + threadIdx.x;      // 392 blocks, exact
    int co = idx & 31;
    int t = idx >> 5;
    int b = t / 196, px = t - b*196;
    int ho = px / 14, wo = px - ho*14;
    const float* src = g3 + (size_t)b*16*784;
    const float* wp = w4 + co*144;
    float acc = b4[co];
    for (int ci = 0; ci < 16; ++ci) {
        #pragma unroll
        for (int kh = 0; kh < 3; ++kh) {
            int hi = ho*2 - 1 + kh;
            if ((unsigned)hi >= 28u) continue;
            #pragma unroll
            for (int kw = 0; kw < 3; ++kw) {
                int wi = wo*2 - 1 + kw;
                if ((unsigned)wi >= 28u) continue;
                acc = fmaf(src[ci*784 + hi*28 + wi], wp[ci*9 + kh*3 + kw], acc);
            }
        }
    }
    g4o[(size_t)b*6272 + px*32 + co] = gelu_t(acc);
}

// ---------------- g5 + avgpool: 32->64, 14->7, s2; atomic pool into gc ----------------
__global__ __launch_bounds__(256) void g5_k(
    const float* __restrict__ g4o, const float* __restrict__ w5,
    const float* __restrict__ b5, float* __restrict__ gc)
{
    int idx = blockIdx.x*256 + threadIdx.x;      // 196 blocks, exact
    int co = idx & 63;
    int t = idx >> 6;
    int b = t / 49, px = t - b*49;
    int ho = px / 7, wo = px - ho*7;
    const float* src = g4o + (size_t)b*6272;
    const float* wp = w5 + co*288;
    float acc = b5[co];
    for (int ci = 0; ci < 32; ++ci) {
        #pragma unroll
        for (int kh = 0; kh < 3; ++kh) {
            int hi = ho*2 - 1 + kh;
            if ((unsigned)hi >= 14u) continue;
            #pragma unroll
            for (int kw = 0; kw < 3; ++kw) {
                int wi = wo*2 - 1 + kw;
                if ((unsigned)wi >= 14u) continue;
                acc = fmaf(src[(hi*14 + wi)*32 + ci], wp[ci*9 + kh*3 + kw], acc);
            }
        }
    }
    atomicAdd(&gc[b*64 + co], gelu_t(acc) * (1.0f/49.0f));
}

// ---------------- hgc: effective head bias  hgc[b][n] = hb1[n] + sum_c gc[b,c]*hw1[n,512+c] ----------------
__global__ __launch_bounds__(256) void hgc_k(
    const float* __restrict__ gc, const float* __restrict__ hw1,
    const float* __restrict__ hb1, float* __restrict__ hgc)
{
    int idx = blockIdx.x*256 + threadIdx.x;   // 32 blocks = 8192
    int b = idx >> 9, n = idx & 511;
    const float* g = gc + b*64;
    const float* w = hw1 + (size_t)n*576 + 512;
    float s = hb1[n];
    #pragma unroll
    for (int c = 0; c < 64; ++c) s = fmaf(g[c], w[c], s);
    hgc[idx] = s;
}

// ---------------- weight conversions + out init + gc zero ----------------
__global__ void cvtall_k(const float* __restrict__ lw1, const float* __restrict__ lw2,
                         const float* __restrict__ hw1, unsigned short* __restrict__ blw1,
                         unsigned short* __restrict__ blw2, unsigned short* __restrict__ bhw1,
                         float* __restrict__ out, const float* __restrict__ b2,
                         float* __restrict__ gc){
    int i = blockIdx.x*blockDim.x + threadIdx.x;
    if (i < M_TOT) out[i] = b2[0];
    if (i < 1024) gc[i] = 0.f;
    if (i < 256*64) {
        int r = i >> 6, c = i & 63;
        blw1[i] = (c < 48) ? f2bf(lw1[r*48 + c]) : 0;
        return;
    }
    int j = i - 256*64;
    if (j < 256*256) { blw2[j] = f2bf(lw2[j]); return; }
    j -= 256*256;
    if (j < 512*576) bhw1[j] = f2bf(hw1[j]);
}

// ================= mlp12: embed + mlp1 + mlp2 + patch fill, M-strip 128, ldc=512 =================
// gemm2 B-fragments read DIRECT from global (L2-hot). gc columns ELIMINATED (folded into hgc).
__global__ __launch_bounds__(512) void mlp12_k(
    const float* __restrict__ points,
    const unsigned short* __restrict__ W1, const float* __restrict__ b1,
    const unsigned short* __restrict__ W2, const float* __restrict__ b2,
    unsigned short* __restrict__ C,
    const float4* __restrict__ fmap4)
{
    __shared__ unsigned short Hd[128*256];   // 64 KB
    int tid = threadIdx.x;
    int wv = tid >> 6, lane = tid & 63;
    int q = lane >> 4, lr = lane & 15;
    int mi = wv >> 2, ni = wv & 3;
    size_t m0 = (size_t)blockIdx.x * 128;

    f4v acc1[4][4];
    #pragma unroll
    for (int i = 0; i < 4; ++i)
        #pragma unroll
        for (int j = 0; j < 4; ++j) acc1[i][j] = (f4v){0.f,0.f,0.f,0.f};

    #pragma unroll
    for (int kb = 0; kb < 2; ++kb) {
        int seg = kb*4 + q;
        s8v a[4], b[4];
        #pragma unroll
        for (int t = 0; t < 4; ++t) {
            size_t m = m0 + mi*64 + t*16 + lr;
            float px = points[m*2], py = points[m*2+1];
            union { s8v v; unsigned short u[8]; } pk;
            #pragma unroll
            for (int j = 0; j < 8; ++j) {
                int k = seg*8 + j;
                unsigned short val = 0;
                if (k < 48) {
                    int i2 = k >> 2, rr = k & 3;
                    float f = (float)(1 << i2);
                    float p = (rr & 1) ? py : px;
                    float s = f * p;
                    val = f2bf((rr < 2) ? __sinf(s) : __cosf(s));
                }
                pk.u[j] = val;
            }
            a[t] = pk.v;
        }
        #pragma unroll
        for (int t = 0; t < 4; ++t) {
            int n = ni*64 + t*16 + lr;
            b[t] = *(const s8v*)(W1 + n*64 + seg*8);
        }
        #pragma unroll
        for (int mt = 0; mt < 4; ++mt)
            #pragma unroll
            for (int nt = 0; nt < 4; ++nt)
                acc1[mt][nt] = __builtin_amdgcn_mfma_f32_16x16x32_bf16(a[mt], b[nt], acc1[mt][nt], 0, 0, 0);
    }
    {
        float b1v[4];
        #pragma unroll
        for (int nt = 0; nt < 4; ++nt) b1v[nt] = b1[ni*64 + nt*16 + lr];
        #pragma unroll
        for (int mt = 0; mt < 4; ++mt)
            #pragma unroll
            for (int r4 = 0; r4 < 4; ++r4) {
                int row = mi*64 + mt*16 + q*4 + r4;
                #pragma unroll
                for (int nt = 0; nt < 4; ++nt) {
                    int col = ni*64 + nt*16 + lr;
                    float v = gelu_t(acc1[mt][nt][r4] + b1v[nt]);
                    int p = (col >> 3) ^ (row & 7);
                    Hd[(row*32 + p)*8 + (col & 7)] = f2bf(v);
                }
            }
    }
    __syncthreads();

    // gemm2: A from Hd (LDS), B direct from global (L2-hot lw2), no in-loop barriers
    f4v acc2[4][4];
    #pragma unroll
    for (int i = 0; i < 4; ++i)
        #pragma unroll
        for (int j = 0; j < 4; ++j) acc2[i][j] = (f4v){0.f,0.f,0.f,0.f};

    #pragma unroll 2
    for (int kt = 0; kt < 8; ++kt) {
        s8v a[4], b[4];
        #pragma unroll
        for (int t = 0; t < 4; ++t) {
            int n = ni*64 + t*16 + lr;
            b[t] = *(const s8v*)(W2 + (size_t)n*256 + kt*32 + q*8);
        }
        #pragma unroll
        for (int t = 0; t < 4; ++t) {
            int row = mi*64 + t*16 + lr;
            int p = (kt*4 + q) ^ (row & 7);
            a[t] = *(const s8v*)(Hd + (row*32 + p)*8);
        }
        #pragma unroll
        for (int mt = 0; mt < 4; ++mt)
            #pragma unroll
            for (int nt = 0; nt < 4; ++nt)
                acc2[mt][nt] = __builtin_amdgcn_mfma_f32_16x16x32_bf16(a[mt], b[nt], acc2[mt][nt], 0, 0, 0);
    }
    {
        float b2v[4];
        #pragma unroll
        for (int nt = 0; nt < 4; ++nt) b2v[nt] = b2[ni*64 + nt*16 + lr];
        #pragma unroll
        for (int mt = 0; mt < 4; ++mt)
            #pragma unroll
            for (int r4 = 0; r4 < 4; ++r4) {
                size_t m = m0 + mi*64 + mt*16 + q*4 + r4;
                #pragma unroll
                for (int nt = 0; nt < 4; ++nt) {
                    int n = ni*64 + nt*16 + lr;
                    C[m*512 + n] = f2bf(acc2[mt][nt][r4] + b2v[nt]);
                }
            }
    }
    #pragma unroll 2
    for (int it = 0; it < 16; ++it) {
        int task = it*512 + tid;
        int ml = task >> 6, ij = task & 63;
        size_t m = m0 + ml;
        int i = ij >> 3, j = ij & 7;
        int b = (int)(m >> 12);
        float px = points[m*2], py = points[m*2+1];
        float cx = px*2.f - 1.f, cy = py*2.f - 1.f;
        const float step = 2.0f/55.0f;
        float gx = cx + ((float)i - 3.5f)*step;
        float gy = cy + ((float)j - 3.5f)*step;
        float ix = (gx + 1.f)*0.5f*55.f;
        float iy = (gy + 1.f)*0.5f*55.f;
        float x0f = floorf(ix), y0f = floorf(iy);
        int x0 = (int)x0f, y0 = (int)y0f;
        int x1 = x0 + 1,  y1 = y0 + 1;
        float wx1 = ix - x0f, wx0 = 1.f - wx1;
        float wy1 = iy - y0f, wy0 = 1.f - wy1;
        float v00 = ((x0>=0)&&(x0<56)&&(y0>=0)&&(y0<56)) ? 1.f : 0.f;
        float v10 = ((x1>=0)&&(x1<56)&&(y0>=0)&&(y0<56)) ? 1.f : 0.f;
        float v01 = ((x0>=0)&&(x0<56)&&(y1>=0)&&(y1<56)) ? 1.f : 0.f;
        float v11 = ((x1>=0)&&(x1<56)&&(y1>=0)&&(y1<56)) ? 1.f : 0.f;
        float w00 = wx0*wy0*v00, w10 = wx1*wy0*v10, w01 = wx0*wy1*v01, w11 = wx1*wy1*v11;
        int cx0 = min(max(x0,0),55), cx1 = min(max(x1,0),55);
        int cy0 = min(max(y0,0),55), cy1 = min(max(y1,0),55);
        const float4* fb = fmap4 + (size_t)b*3136;
        float4 f00 = fb[cy0*56 + cx0], f10 = fb[cy0*56 + cx1];
        float4 f01 = fb[cy1*56 + cx0], f11 = fb[cy1*56 + cx1];
        float4 v;
        v.x = w00*f00.x + w10*f10.x + w01*f01.x + w11*f11.x;
        v.y = w00*f00.y + w10*f10.y + w01*f01.y + w11*f11.y;
        v.z = w00*f00.z + w10*f10.z + w01*f01.z + w11*f11.z;
        v.w = w00*f00.w + w10*f10.w + w01*f01.w + w11*f11.w;
        C[m*512 + 256 +   0 + ij] = f2bf(v.x);
        C[m*512 + 256 +  64 + ij] = f2bf(v.y);
        C[m*512 + 256 + 128 + ij] = f2bf(v.z);
        C[m*512 + 256 + 192 + ij] = f2bf(v.w);
    }
}

// ================= head: 256 thr, M-strip 64, N-split 2, BK=64, K=512, bias from hgc =================
__global__ __launch_bounds__(256, 3) void gemm_hd_k(
    const unsigned short* __restrict__ A,
    const unsigned short* __restrict__ W,
    const float* __restrict__ hgc, const float* __restrict__ w2,
    float* __restrict__ out)
{
    __shared__ unsigned short As[64*HBK];    // 8 KB
    __shared__ unsigned short Bs[256*HBK];   // 32 KB
    __shared__ float red[4*64];
    int tid = threadIdx.x;
    int wv = tid >> 6, lane = tid & 63;
    int q = lane >> 4, lr = lane & 15;
    int nq = wv * 64;
    size_t m0 = (size_t)blockIdx.x * 64;
    int nbase = blockIdx.y * 256;
    int bimg = (int)(m0 >> 12);              // image index, uniform per block

    const unsigned short* srcA[2]; unsigned short* dstA[2];
    #pragma unroll
    for (int r = 0; r < 2; ++r) {
        int f = r*256 + tid;
        int row = f >> 3, sl = (f & 7) ^ (row & 7);
        srcA[r] = A + (m0 + row)*512 + sl*8;
        dstA[r] = As + f*8;
    }
    const unsigned short* srcB[8]; unsigned short* dstB[8];
    #pragma unroll
    for (int r = 0; r < 8; ++r) {
        int f = r*256 + tid;
        int row = f >> 3, sl = (f & 7) ^ (row & 7);
        srcB[r] = W + (size_t)(nbase + row)*576 + sl*8;
        dstB[r] = Bs + f*8;
    }

    f4v acc[4][4];
    #pragma unroll
    for (int i = 0; i < 4; ++i)
        #pragma unroll
        for (int j = 0; j < 4; ++j) acc[i][j] = (f4v){0.f,0.f,0.f,0.f};

    for (int k0 = 0; k0 < 512; k0 += HBK) {
        #pragma unroll
        for (int r = 0; r < 2; ++r) { GLL(srcA[r], dstA[r]); srcA[r] += HBK; }
        #pragma unroll
        for (int r = 0; r < 8; ++r) { GLL(srcB[r], dstB[r]); srcB[r] += HBK; }
        __syncthreads();
        #pragma unroll
        for (int kk = 0; kk < 2; ++kk) {
            s8v a[4], b[4];
            #pragma unroll
            for (int t = 0; t < 4; ++t) {
                int row = t*16 + lr;
                int ph = (kk*4 + q) ^ (row & 7);
                a[t] = *(const s8v*)(As + (row*8 + ph)*8);
            }
            #pragma unroll
            for (int t = 0; t < 4; ++t) {
                int row = nq + t*16 + lr;
                int ph = (kk*4 + q) ^ (row & 7);
                b[t] = *(const s8v*)(Bs + (row*8 + ph)*8);
            }
            #pragma unroll
            for (int mt = 0; mt < 4; ++mt)
                #pragma unroll
                for (int nt = 0; nt < 4; ++nt)
                    acc[mt][nt] = __builtin_amdgcn_mfma_f32_16x16x32_bf16(a[mt], b[nt], acc[mt][nt], 0, 0, 0);
        }
        __syncthreads();
    }
    float bv[4], w2v[4];
    #pragma unroll
    for (int nt = 0; nt < 4; ++nt) {
        int n = nbase + nq + nt*16 + lr;
        bv[nt] = hgc[bimg*512 + n];
        w2v[nt] = w2[n];
    }
    #pragma unroll
    for (int mt = 0; mt < 4; ++mt)
        #pragma unroll
        for (int r4 = 0; r4 < 4; ++r4) {
            int ml = mt*16 + q*4 + r4;
            float s = 0.f;
            #pragma unroll
            for (int nt = 0; nt < 4; ++nt)
                s += gelu_t(acc[mt][nt][r4] + bv[nt]) * w2v[nt];
            #pragma unroll
            for (int off = 8; off > 0; off >>= 1) s += __shfl_down(s, off, 16);
            if (lr == 0) red[wv*64 + ml] = s;
        }
    __syncthreads();
    if (tid < 64) {
        float t = red[tid] + red[64 + tid] + red[128 + tid] + red[192 + tid];
        atomicAdd(&out[m0 + tid], t);
    }
}

extern "C" void kernel_launch(void* const* d_in, const int* in_sizes, int n_in,
                              void* d_out, int out_size, void* d_ws, size_t ws_size,
                              hipStream_t stream) {
    const float* points = (const float*)d_in[0];
    const float* images = (const float*)d_in[1];
    const float* pw1 = (const float*)d_in[2];  const float* pb1 = (const float*)d_in[3];
    const float* pw2 = (const float*)d_in[4];  const float* pb2 = (const float*)d_in[5];
    const float* pw3 = (const float*)d_in[6];  const float* pb3 = (const float*)d_in[7];
    const float* gw1 = (const float*)d_in[8];  const float* gb1 = (const float*)d_in[9];
    const float* gw2 = (const float*)d_in[10]; const float* gb2 = (const float*)d_in[11];
    const float* gw3 = (const float*)d_in[12]; const float* gb3 = (const float*)d_in[13];
    const float* gw4 = (const float*)d_in[14]; const float* gb4 = (const float*)d_in[15];
    const float* gw5 = (const float*)d_in[16]; const float* gb5 = (const float*)d_in[17];
    const float* lw1 = (const float*)d_in[18]; const float* lb1 = (const float*)d_in[19];
    const float* lw2 = (const float*)d_in[20]; const float* lb2 = (const float*)d_in[21];
    const float* hw1 = (const float*)d_in[22]; const float* hb1 = (const float*)d_in[23];
    const float* hw2 = (const float*)d_in[24]; const float* hb2 = (const float*)d_in[25];
    float* out = (float*)d_out;

    // ---- workspace layout ----
    char* base = (char*)d_ws;
    unsigned short* fused_b = (unsigned short*)base;                       // M*512 bf16 = 67 MB
    float4* fmap4 = (float4*)(fused_b + (size_t)M_TOT*512);                // 16*3136 float4
    float* gc   = (float*)(fmap4 + (size_t)16*3136);                       // 1024
    float* hgc  = gc + 1024;                                               // 16*512
    unsigned short* blw1 = (unsigned short*)(hgc + 16*512);                // 256*64
    unsigned short* blw2 = blw1 + 256*64;                                  // 256*256
    unsigned short* bhw1 = blw2 + 256*256;                                 // 512*576
    // conv temps alias inside the fused region (dead before mlp12 writes fused):
    float* ct = (float*)base;
    float* f1 = ct;
    float* f2 = f1 + (size_t)16*16*112*112;
    float* g1 = f2 + (size_t)16*32*56*56;
    float* g2 = g1 + (size_t)16*4*112*112;
    float* g3 = g2 + (size_t)16*8*56*56;
    float* g4 = g3 + (size_t)16*16*28*28;    // NHWC [b][196][32]

    cvtall_k<<<1472, 256, 0, stream>>>(lw1, lw2, hw1, blw1, blw2, bhw1, out, hb2, gc);
    conv_dual_k<<<dim3(7,7,16), 256, 0, stream>>>(images, pw1, pb1, gw1, gb1, f1, g1);
    conv_pg2_k<<<dim3(4,4,48), 256, 0, stream>>>(f1, pw2, pb2, f2, g1, gw2, gb2, g2);
    conv_pg3_k<<<dim3(13,1,32), 256, 0, stream>>>(f2, pw3, pb3, fmap4, g2, gw3, gb3, g3);
    g4_k<<<392, 256, 0, stream>>>(g3, gw4, gb4, g4);
    g5_k<<<196, 256, 0, stream>>>(g4, gw5, gb5, gc);   // includes avgpool via atomics
    hgc_k<<<32, 256, 0, stream>>>(gc, hw1, hb1, hgc);  // fold gc into head bias (fp32)
    // mlp12 AFTER conv tail (conv temps alias inside fused region)
    mlp12_k<<<M_TOT/128, 512, 0, stream>>>(points, blw1, lb1, blw2, lb2, fused_b, fmap4);
    gemm_hd_k<<<dim3(M_TOT/64, 2), 256, 0, stream>>>(fused_b, bhw1, hgc, hw2, out);
}

// Round 20
// 419.414 us; speedup vs baseline: 1.0717x; 1.0198x over previous
//
#include <hip/hip_runtime.h>
#include <math.h>

#define BB 16
#define NN 4096
#define M_TOT (BB*NN)   // 65536 points
#define HBK 64

typedef __attribute__((ext_vector_type(8))) short s8v;   // 8 bf16 = 4 VGPRs
typedef __attribute__((ext_vector_type(4))) float f4v;

// exact tanh-GELU via sigmoid identity: 0.5x(1+tanh(z)) = x * sigmoid(2z)
__device__ __forceinline__ float gelu_t(float x){
    float u = 1.5957691216057308f * x * (1.0f + 0.044715f*x*x);
    return x / (1.0f + __expf(-u));
}

__device__ __forceinline__ unsigned short f2bf(float f){
    unsigned int u = __float_as_uint(f);
    u += 0x7fffu + ((u >> 16) & 1u);
    return (unsigned short)(u >> 16);
}

#define GLL(src, dst) __builtin_amdgcn_global_load_lds( \
    (const __attribute__((address_space(1))) void*)(src), \
    (__attribute__((address_space(3))) void*)(dst), 16, 0, 0)

// ---------------- chunked-staging conv device fn: CHUNK channels per barrier ----------------
template<int CIN, int COUT, int STRIDE, int CHUNK>
__device__ __forceinline__ void conv_dev2(
    const float* __restrict__ in, const float* __restrict__ w,
    const float* __restrict__ bias, float* __restrict__ out,
    int Hin, int Win, int Hout, int Wout, int bx, int by, int b, float* tile)
{
    constexpr int IW = 15*STRIDE + 3;
    constexpr int IH = IW;
    constexpr int PITCH = IW + 1;
    int tid = threadIdx.x;
    int tx = tid & 15, ty = tid >> 4;
    int wo = bx*16 + tx;
    int ho = by*16 + ty;
    int win0 = bx*16*STRIDE - 1;
    int hin0 = by*16*STRIDE - 1;
    bool valid = (wo < Wout) && (ho < Hout);

    float acc[COUT];
    #pragma unroll
    for (int co = 0; co < COUT; ++co) acc[co] = bias[co];

    const float* ib = in + (size_t)(b*CIN)*Hin*Win;
    for (int ci0 = 0; ci0 < CIN; ci0 += CHUNK) {
        __syncthreads();
        for (int idx = tid; idx < CHUNK*IH*IW; idx += 256) {
            int c = idx / (IH*IW), rem = idx - c*(IH*IW);
            int r = rem / IW, cc = rem - r*IW;
            int hi = hin0 + r, wi = win0 + cc;
            float v = 0.f;
            if ((unsigned)hi < (unsigned)Hin && (unsigned)wi < (unsigned)Win)
                v = ib[(size_t)(ci0 + c)*Hin*Win + hi*Win + wi];
            tile[c*IH*PITCH + r*PITCH + cc] = v;
        }
        __syncthreads();
        for (int ci = 0; ci < CHUNK; ++ci) {
            float vv[9];
            const float* tb = tile + ci*IH*PITCH;
            #pragma unroll
            for (int kh = 0; kh < 3; ++kh)
                #pragma unroll
                for (int kw = 0; kw < 3; ++kw)
                    vv[kh*3+kw] = tb[(ty*STRIDE + kh)*PITCH + tx*STRIDE + kw];
            const float* wc = w + (ci0 + ci)*9;
            #pragma unroll
            for (int co = 0; co < COUT; ++co) {
                const float* wp = wc + co*CIN*9;
                #pragma unroll
                for (int k = 0; k < 9; ++k)
                    acc[co] = fmaf(vv[k], wp[k], acc[co]);
            }
        }
    }
    if (valid) {
        size_t obase = ((size_t)b*COUT)*Hout*Wout + (size_t)ho*Wout + wo;
        #pragma unroll
        for (int co = 0; co < COUT; ++co)
            out[obase + (size_t)co*Hout*Wout] = gelu_t(acc[co]);
    }
}

// ---------------- dual conv1: plane (16ch) + global (4ch), all 3 ci staged once ----------------
__global__ __launch_bounds__(256) void conv_dual_k(
    const float* __restrict__ in,
    const float* __restrict__ wA, const float* __restrict__ bA,
    const float* __restrict__ wB, const float* __restrict__ bB,
    float* __restrict__ outA, float* __restrict__ outB)
{
    __shared__ float tile[3*33*34];   // 13.5 KB
    const int Hin = 224, Win = 224, Hout = 112, Wout = 112;
    int tid = threadIdx.x;
    int tx = tid & 15, ty = tid >> 4;
    int b = blockIdx.z;
    int wo = blockIdx.x*16 + tx;
    int ho = blockIdx.y*16 + ty;
    int win0 = blockIdx.x*32 - 1;
    int hin0 = blockIdx.y*32 - 1;

    const float* ib = in + (size_t)(b*3)*Hin*Win;
    for (int idx = tid; idx < 3*1089; idx += 256) {
        int c = idx / 1089, rem = idx - c*1089;
        int r = rem / 33, cc = rem - r*33;
        int hi = hin0 + r, wi = win0 + cc;
        float v = 0.f;
        if ((unsigned)hi < (unsigned)Hin && (unsigned)wi < (unsigned)Win)
            v = ib[(size_t)c*Hin*Win + hi*Win + wi];
        tile[c*33*34 + r*34 + cc] = v;
    }
    __syncthreads();

    float accA[16], accB[4];
    #pragma unroll
    for (int co = 0; co < 16; ++co) accA[co] = bA[co];
    #pragma unroll
    for (int co = 0; co < 4; ++co) accB[co] = bB[co];

    #pragma unroll
    for (int ci = 0; ci < 3; ++ci) {
        float vv[9];
        const float* tb = tile + ci*33*34;
        #pragma unroll
        for (int kh = 0; kh < 3; ++kh)
            #pragma unroll
            for (int kw = 0; kw < 3; ++kw)
                vv[kh*3+kw] = tb[(ty*2 + kh)*34 + tx*2 + kw];
        #pragma unroll
        for (int co = 0; co < 16; ++co) {
            const float* wp = wA + co*27 + ci*9;
            #pragma unroll
            for (int k = 0; k < 9; ++k) accA[co] = fmaf(vv[k], wp[k], accA[co]);
        }
        #pragma unroll
        for (int co = 0; co < 4; ++co) {
            const float* wp = wB + co*27 + ci*9;
            #pragma unroll
            for (int k = 0; k < 9; ++k) accB[co] = fmaf(vv[k], wp[k], accB[co]);
        }
    }
    size_t px = (size_t)ho*Wout + wo;
    #pragma unroll
    for (int co = 0; co < 16; ++co)
        outA[((size_t)(b*16 + co))*Hout*Wout + px] = gelu_t(accA[co]);
    #pragma unroll
    for (int co = 0; co < 4; ++co)
        outB[((size_t)(b*4 + co))*Hout*Wout + px] = gelu_t(accB[co]);
}

// ---------------- layer-2 convs: plane p2 (16->32, split co 2x16) + global g2 (4->8) ----------------
__global__ __launch_bounds__(256) void conv_pg2_k(
    const float* __restrict__ f1, const float* __restrict__ pw2, const float* __restrict__ pb2, float* __restrict__ f2,
    const float* __restrict__ g1, const float* __restrict__ gw2, const float* __restrict__ gb2, float* __restrict__ g2)
{
    __shared__ float tile[8*33*34];   // 35.9 KB
    int z = blockIdx.z;
    if (z < 32) {
        int b = z >> 1, half = z & 1;
        conv_dev2<16,16,2,8>(f1 + (size_t)b*16*12544, pw2 + half*2304, pb2 + half*16,
                             f2 + ((size_t)(b*32 + half*16))*3136,
                             112,112, 56,56, blockIdx.x, blockIdx.y, 0, tile);
    } else {
        conv_dev2<4,8,2,4>(g1, gw2, gb2, g2, 112,112, 56,56, blockIdx.x, blockIdx.y, z-32, tile);
    }
}

// ---------------- layer-3: plane p3 DIRECT (32->4, NHWC out) + global g3 (8->16, LDS) ----------------
__global__ __launch_bounds__(256) void conv_pg3_k(
    const float* __restrict__ f2, const float* __restrict__ pw3, const float* __restrict__ pb3, float4* __restrict__ fmap4,
    const float* __restrict__ g2, const float* __restrict__ gw3, const float* __restrict__ gb3, float* __restrict__ g3)
{
    __shared__ float tile[8*33*34];
    int z = blockIdx.z;
    if (z < 16) {
        int b = z;
        int idx = blockIdx.x*256 + threadIdx.x;
        if (idx >= 3136) return;
        int ho = idx / 56, wo = idx - ho*56;
        const float* ib = f2 + (size_t)b*32*3136;
        float acc[4];
        #pragma unroll
        for (int co = 0; co < 4; ++co) acc[co] = pb3[co];
        for (int ci = 0; ci < 32; ++ci) {
            const float* ic = ib + (size_t)ci*3136;
            #pragma unroll
            for (int kh = 0; kh < 3; ++kh) {
                int hi = ho - 1 + kh;
                if ((unsigned)hi >= 56u) continue;
                #pragma unroll
                for (int kw = 0; kw < 3; ++kw) {
                    int wi = wo - 1 + kw;
                    if ((unsigned)wi >= 56u) continue;
                    float v = ic[hi*56 + wi];
                    int wofs = ci*9 + kh*3 + kw;
                    #pragma unroll
                    for (int co = 0; co < 4; ++co)
                        acc[co] = fmaf(v, pw3[co*288 + wofs], acc[co]);
                }
            }
        }
        float4 o;
        o.x = gelu_t(acc[0]); o.y = gelu_t(acc[1]);
        o.z = gelu_t(acc[2]); o.w = gelu_t(acc[3]);
        fmap4[(size_t)b*3136 + idx] = o;
    } else {
        if (blockIdx.x >= 4) return;
        int bx = blockIdx.x & 1, by = blockIdx.x >> 1;
        conv_dev2<8,16,2,8>(g2, gw3, gb3, g3, 56,56, 28,28, bx, by, z-16, tile);
    }
}

// ================= K4: g4 (392 blocks) + patch fill (16384 blocks, ushort4 stores) =================
__global__ __launch_bounds__(256) void k4_k(
    const float* __restrict__ g3, const float* __restrict__ w4,
    const float* __restrict__ b4, float* __restrict__ g4o,
    const float4* __restrict__ fmap4, const float* __restrict__ points,
    unsigned short* __restrict__ C)
{
    int bid = blockIdx.x;
    int tid = threadIdx.x;
    if (bid < 392) {
        int idx = bid*256 + tid;
        int co = idx & 31;
        int t = idx >> 5;
        int b = t / 196, px = t - b*196;
        int ho = px / 14, wo = px - ho*14;
        const float* src = g3 + (size_t)b*16*784;
        const float* wp = w4 + co*144;
        float acc = b4[co];
        for (int ci = 0; ci < 16; ++ci) {
            #pragma unroll
            for (int kh = 0; kh < 3; ++kh) {
                int hi = ho*2 - 1 + kh;
                if ((unsigned)hi >= 28u) continue;
                #pragma unroll
                for (int kw = 0; kw < 3; ++kw) {
                    int wi = wo*2 - 1 + kw;
                    if ((unsigned)wi >= 28u) continue;
                    acc = fmaf(src[ci*784 + hi*28 + wi], wp[ci*9 + kh*3 + kw], acc);
                }
            }
        }
        g4o[(size_t)b*6272 + px*32 + co] = gelu_t(acc);
    } else {
        int task = (bid - 392)*256 + tid;     // M*64 tasks, exact
        int ml = task >> 6, ij = task & 63;
        size_t m = (size_t)ml;
        int i = ij >> 3, j = ij & 7;
        int b = (int)(m >> 12);
        float px = points[m*2], py = points[m*2+1];
        float cx = px*2.f - 1.f, cy = py*2.f - 1.f;
        const float step = 2.0f/55.0f;
        float gx = cx + ((float)i - 3.5f)*step;
        float gy = cy + ((float)j - 3.5f)*step;
        float ix = (gx + 1.f)*0.5f*55.f;
        float iy = (gy + 1.f)*0.5f*55.f;
        float x0f = floorf(ix), y0f = floorf(iy);
        int x0 = (int)x0f, y0 = (int)y0f;
        int x1 = x0 + 1,  y1 = y0 + 1;
        float wx1 = ix - x0f, wx0 = 1.f - wx1;
        float wy1 = iy - y0f, wy0 = 1.f - wy1;
        float v00 = ((x0>=0)&&(x0<56)&&(y0>=0)&&(y0<56)) ? 1.f : 0.f;
        float v10 = ((x1>=0)&&(x1<56)&&(y0>=0)&&(y0<56)) ? 1.f : 0.f;
        float v01 = ((x0>=0)&&(x0<56)&&(y1>=0)&&(y1<56)) ? 1.f : 0.f;
        float v11 = ((x1>=0)&&(x1<56)&&(y1>=0)&&(y1<56)) ? 1.f : 0.f;
        float w00 = wx0*wy0*v00, w10 = wx1*wy0*v10, w01 = wx0*wy1*v01, w11 = wx1*wy1*v11;
        int cx0 = min(max(x0,0),55), cx1 = min(max(x1,0),55);
        int cy0 = min(max(y0,0),55), cy1 = min(max(y1,0),55);
        const float4* fb = fmap4 + (size_t)b*3136;
        float4 f00 = fb[cy0*56 + cx0], f10 = fb[cy0*56 + cx1];
        float4 f01 = fb[cy1*56 + cx0], f11 = fb[cy1*56 + cx1];
        float4 v;
        v.x = w00*f00.x + w10*f10.x + w01*f01.x + w11*f11.x;
        v.y = w00*f00.y + w10*f10.y + w01*f01.y + w11*f11.y;
        v.z = w00*f00.z + w10*f10.z + w01*f01.z + w11*f11.z;
        v.w = w00*f00.w + w10*f10.w + w01*f01.w + w11*f11.w;
        // interleaved patch layout: stored col 256 + ij*4 + c  (bhw1 permuted to match)
        ushort4 o;
        o.x = f2bf(v.x); o.y = f2bf(v.y); o.z = f2bf(v.z); o.w = f2bf(v.w);
        *(ushort4*)(C + m*512 + 256 + ij*4) = o;
    }
}

// ---------------- g5 + avgpool: 32->64, 14->7, s2; atomic pool into gc ----------------
__global__ __launch_bounds__(256) void g5_k(
    const float* __restrict__ g4o, const float* __restrict__ w5,
    const float* __restrict__ b5, float* __restrict__ gc)
{
    int idx = blockIdx.x*256 + threadIdx.x;      // 196 blocks, exact
    int co = idx & 63;
    int t = idx >> 6;
    int b = t / 49, px = t - b*49;
    int ho = px / 7, wo = px - ho*7;
    const float* src = g4o + (size_t)b*6272;
    const float* wp = w5 + co*288;
    float acc = b5[co];
    for (int ci = 0; ci < 32; ++ci) {
        #pragma unroll
        for (int kh = 0; kh < 3; ++kh) {
            int hi = ho*2 - 1 + kh;
            if ((unsigned)hi >= 14u) continue;
            #pragma unroll
            for (int kw = 0; kw < 3; ++kw) {
                int wi = wo*2 - 1 + kw;
                if ((unsigned)wi >= 14u) continue;
                acc = fmaf(src[(hi*14 + wi)*32 + ci], wp[ci*9 + kh*3 + kw], acc);
            }
        }
    }
    atomicAdd(&gc[b*64 + co], gelu_t(acc) * (1.0f/49.0f));
}

// ---------------- hgc: effective head bias  hgc[b][n] = hb1[n] + sum_c gc[b,c]*hw1[n,512+c] ----------------
__global__ __launch_bounds__(256) void hgc_k(
    const float* __restrict__ gc, const float* __restrict__ hw1,
    const float* __restrict__ hb1, float* __restrict__ hgc)
{
    int idx = blockIdx.x*256 + threadIdx.x;   // 32 blocks = 8192
    int b = idx >> 9, n = idx & 511;
    const float* g = gc + b*64;
    const float* w = hw1 + (size_t)n*576 + 512;
    float s = hb1[n];
    #pragma unroll
    for (int c = 0; c < 64; ++c) s = fmaf(g[c], w[c], s);
    hgc[idx] = s;
}

// ---------------- weight conversions (bhw1 col-permuted for k in [256,512)) + out init + gc zero ----------------
__global__ void cvtall_k(const float* __restrict__ lw1, const float* __restrict__ lw2,
                         const float* __restrict__ hw1, unsigned short* __restrict__ blw1,
                         unsigned short* __restrict__ blw2, unsigned short* __restrict__ bhw1,
                         float* __restrict__ out, const float* __restrict__ b2,
                         float* __restrict__ gc){
    int i = blockIdx.x*blockDim.x + threadIdx.x;
    if (i < M_TOT) out[i] = b2[0];
    if (i < 1024) gc[i] = 0.f;
    if (i < 256*64) {
        int r = i >> 6, c = i & 63;
        blw1[i] = (c < 48) ? f2bf(lw1[r*48 + c]) : 0;
        return;
    }
    int j = i - 256*64;
    if (j < 256*256) { blw2[j] = f2bf(lw2[j]); return; }
    j -= 256*256;
    if (j < 512*576) {
        int n = j / 576, k = j - n*576;
        int src_k = k;
        if (k >= 256 && k < 512) {
            int s = k - 256;
            src_k = 256 + (s & 3)*64 + (s >> 2);   // stored ij*4+c  <-  semantic c*64+ij
        }
        bhw1[j] = f2bf(hw1[(size_t)n*576 + src_k]);
    }
}

// ================= mlp12: embed(shared) + mlp1 + mlp2 -> fused cols 0..255, M-strip 128 =================
// pe computed ONCE into LDS (no 4x redundant sinf); gemm2 B direct from global (L2-hot).
__global__ __launch_bounds__(512) void mlp12_k(
    const float* __restrict__ points,
    const unsigned short* __restrict__ W1, const float* __restrict__ b1,
    const unsigned short* __restrict__ W2, const float* __restrict__ b2,
    unsigned short* __restrict__ C)
{
    __shared__ unsigned short Pe[128*64];    // 16 KB, swizzled (phys chunk = seg ^ (row&7))
    __shared__ unsigned short Hd[128*256];   // 64 KB
    int tid = threadIdx.x;
    int wv = tid >> 6, lane = tid & 63;
    int q = lane >> 4, lr = lane & 15;
    int mi = wv >> 2, ni = wv & 3;
    size_t m0 = (size_t)blockIdx.x * 128;

    // ---- embed -> Pe (each chunk computed once) ----
    #pragma unroll
    for (int it = 0; it < 2; ++it) {
        int idx = it*512 + tid;
        int row = idx >> 3, seg = idx & 7;
        size_t m = m0 + row;
        float px = points[m*2], py = points[m*2+1];
        union { s8v v; unsigned short u[8]; } pk;
        #pragma unroll
        for (int j = 0; j < 8; ++j) {
            int k = seg*8 + j;
            unsigned short val = 0;
            if (k < 48) {
                int i2 = k >> 2, rr = k & 3;
                float f = (float)(1 << i2);
                float p = (rr & 1) ? py : px;
                float s = f * p;
                val = f2bf((rr < 2) ? __sinf(s) : __cosf(s));
            }
            pk.u[j] = val;
        }
        *(s8v*)(Pe + (row*8 + (seg ^ (row & 7)))*8) = pk.v;
    }
    __syncthreads();

    // ---- gemm1: hid = gelu(pe @ lw1^T + b1), K=64, A from Pe ----
    f4v acc1[4][4];
    #pragma unroll
    for (int i = 0; i < 4; ++i)
        #pragma unroll
        for (int j = 0; j < 4; ++j) acc1[i][j] = (f4v){0.f,0.f,0.f,0.f};

    #pragma unroll
    for (int kb = 0; kb < 2; ++kb) {
        int seg = kb*4 + q;
        s8v a[4], b[4];
        #pragma unroll
        for (int t = 0; t < 4; ++t) {
            int row = mi*64 + t*16 + lr;
            a[t] = *(const s8v*)(Pe + (row*8 + (seg ^ (row & 7)))*8);
        }
        #pragma unroll
        for (int t = 0; t < 4; ++t) {
            int n = ni*64 + t*16 + lr;
            b[t] = *(const s8v*)(W1 + n*64 + seg*8);
        }
        #pragma unroll
        for (int mt = 0; mt < 4; ++mt)
            #pragma unroll
            for (int nt = 0; nt < 4; ++nt)
                acc1[mt][nt] = __builtin_amdgcn_mfma_f32_16x16x32_bf16(a[mt], b[nt], acc1[mt][nt], 0, 0, 0);
    }
    {
        float b1v[4];
        #pragma unroll
        for (int nt = 0; nt < 4; ++nt) b1v[nt] = b1[ni*64 + nt*16 + lr];
        #pragma unroll
        for (int mt = 0; mt < 4; ++mt)
            #pragma unroll
            for (int r4 = 0; r4 < 4; ++r4) {
                int row = mi*64 + mt*16 + q*4 + r4;
                #pragma unroll
                for (int nt = 0; nt < 4; ++nt) {
                    int col = ni*64 + nt*16 + lr;
                    float v = gelu_t(acc1[mt][nt][r4] + b1v[nt]);
                    int p = (col >> 3) ^ (row & 7);
                    Hd[(row*32 + p)*8 + (col & 7)] = f2bf(v);
                }
            }
    }
    __syncthreads();

    // ---- gemm2: pf = hid @ lw2^T + b2, A from Hd, B direct from global ----
    f4v acc2[4][4];
    #pragma unroll
    for (int i = 0; i < 4; ++i)
        #pragma unroll
        for (int j = 0; j < 4; ++j) acc2[i][j] = (f4v){0.f,0.f,0.f,0.f};

    #pragma unroll 2
    for (int kt = 0; kt < 8; ++kt) {
        s8v a[4], b[4];
        #pragma unroll
        for (int t = 0; t < 4; ++t) {
            int n = ni*64 + t*16 + lr;
            b[t] = *(const s8v*)(W2 + (size_t)n*256 + kt*32 + q*8);
        }
        #pragma unroll
        for (int t = 0; t < 4; ++t) {
            int row = mi*64 + t*16 + lr;
            int p = (kt*4 + q) ^ (row & 7);
            a[t] = *(const s8v*)(Hd + (row*32 + p)*8);
        }
        #pragma unroll
        for (int mt = 0; mt < 4; ++mt)
            #pragma unroll
            for (int nt = 0; nt < 4; ++nt)
                acc2[mt][nt] = __builtin_amdgcn_mfma_f32_16x16x32_bf16(a[mt], b[nt], acc2[mt][nt], 0, 0, 0);
    }
    {
        float b2v[4];
        #pragma unroll
        for (int nt = 0; nt < 4; ++nt) b2v[nt] = b2[ni*64 + nt*16 + lr];
        #pragma unroll
        for (int mt = 0; mt < 4; ++mt)
            #pragma unroll
            for (int r4 = 0; r4 < 4; ++r4) {
                size_t m = m0 + mi*64 + mt*16 + q*4 + r4;
                #pragma unroll
                for (int nt = 0; nt < 4; ++nt) {
                    int n = ni*64 + nt*16 + lr;
                    C[m*512 + n] = f2bf(acc2[mt][nt][r4] + b2v[nt]);
                }
            }
    }
}

// ================= head: 256 thr, M-strip 64, N-split 2, BK=64, K=512, bias from hgc =================
__global__ __launch_bounds__(256, 3) void gemm_hd_k(
    const unsigned short* __restrict__ A,
    const unsigned short* __restrict__ W,
    const float* __restrict__ hgc, const float* __restrict__ w2,
    float* __restrict__ out)
{
    __shared__ unsigned short As[64*HBK];    // 8 KB
    __shared__ unsigned short Bs[256*HBK];   // 32 KB
    __shared__ float red[4*64];
    int tid = threadIdx.x;
    int wv = tid >> 6, lane = tid & 63;
    int q = lane >> 4, lr = lane & 15;
    int nq = wv * 64;
    size_t m0 = (size_t)blockIdx.x * 64;
    int nbase = blockIdx.y * 256;
    int bimg = (int)(m0 >> 12);              // image index, uniform per block

    const unsigned short* srcA[2]; unsigned short* dstA[2];
    #pragma unroll
    for (int r = 0; r < 2; ++r) {
        int f = r*256 + tid;
        int row = f >> 3, sl = (f & 7) ^ (row & 7);
        srcA[r] = A + (m0 + row)*512 + sl*8;
        dstA[r] = As + f*8;
    }
    const unsigned short* srcB[8]; unsigned short* dstB[8];
    #pragma unroll
    for (int r = 0; r < 8; ++r) {
        int f = r*256 + tid;
        int row = f >> 3, sl = (f & 7) ^ (row & 7);
        srcB[r] = W + (size_t)(nbase + row)*576 + sl*8;
        dstB[r] = Bs + f*8;
    }

    f4v acc[4][4];
    #pragma unroll
    for (int i = 0; i < 4; ++i)
        #pragma unroll
        for (int j = 0; j < 4; ++j) acc[i][j] = (f4v){0.f,0.f,0.f,0.f};

    for (int k0 = 0; k0 < 512; k0 += HBK) {
        #pragma unroll
        for (int r = 0; r < 2; ++r) { GLL(srcA[r], dstA[r]); srcA[r] += HBK; }
        #pragma unroll
        for (int r = 0; r < 8; ++r) { GLL(srcB[r], dstB[r]); srcB[r] += HBK; }
        __syncthreads();
        #pragma unroll
        for (int kk = 0; kk < 2; ++kk) {
            s8v a[4], b[4];
            #pragma unroll
            for (int t = 0; t < 4; ++t) {
                int row = t*16 + lr;
                int ph = (kk*4 + q) ^ (row & 7);
                a[t] = *(const s8v*)(As + (row*8 + ph)*8);
            }
            #pragma unroll
            for (int t = 0; t < 4; ++t) {
                int row = nq + t*16 + lr;
                int ph = (kk*4 + q) ^ (row & 7);
                b[t] = *(const s8v*)(Bs + (row*8 + ph)*8);
            }
            #pragma unroll
            for (int mt = 0; mt < 4; ++mt)
                #pragma unroll
                for (int nt = 0; nt < 4; ++nt)
                    acc[mt][nt] = __builtin_amdgcn_mfma_f32_16x16x32_bf16(a[mt], b[nt], acc[mt][nt], 0, 0, 0);
        }
        __syncthreads();
    }
    float bv[4], w2v[4];
    #pragma unroll
    for (int nt = 0; nt < 4; ++nt) {
        int n = nbase + nq + nt*16 + lr;
        bv[nt] = hgc[bimg*512 + n];
        w2v[nt] = w2[n];
    }
    #pragma unroll
    for (int mt = 0; mt < 4; ++mt)
        #pragma unroll
        for (int r4 = 0; r4 < 4; ++r4) {
            int ml = mt*16 + q*4 + r4;
            float s = 0.f;
            #pragma unroll
            for (int nt = 0; nt < 4; ++nt)
                s += gelu_t(acc[mt][nt][r4] + bv[nt]) * w2v[nt];
            #pragma unroll
            for (int off = 8; off > 0; off >>= 1) s += __shfl_down(s, off, 16);
            if (lr == 0) red[wv*64 + ml] = s;
        }
    __syncthreads();
    if (tid < 64) {
        float t = red[tid] + red[64 + tid] + red[128 + tid] + red[192 + tid];
        atomicAdd(&out[m0 + tid], t);
    }
}

extern "C" void kernel_launch(void* const* d_in, const int* in_sizes, int n_in,
                              void* d_out, int out_size, void* d_ws, size_t ws_size,
                              hipStream_t stream) {
    const float* points = (const float*)d_in[0];
    const float* images = (const float*)d_in[1];
    const float* pw1 = (const float*)d_in[2];  const float* pb1 = (const float*)d_in[3];
    const float* pw2 = (const float*)d_in[4];  const float* pb2 = (const float*)d_in[5];
    const float* pw3 = (const float*)d_in[6];  const float* pb3 = (const float*)d_in[7];
    const float* gw1 = (const float*)d_in[8];  const float* gb1 = (const float*)d_in[9];
    const float* gw2 = (const float*)d_in[10]; const float* gb2 = (const float*)d_in[11];
    const float* gw3 = (const float*)d_in[12]; const float* gb3 = (const float*)d_in[13];
    const float* gw4 = (const float*)d_in[14]; const float* gb4 = (const float*)d_in[15];
    const float* gw5 = (const float*)d_in[16]; const float* gb5 = (const float*)d_in[17];
    const float* lw1 = (const float*)d_in[18]; const float* lb1 = (const float*)d_in[19];
    const float* lw2 = (const float*)d_in[20]; const float* lb2 = (const float*)d_in[21];
    const float* hw1 = (const float*)d_in[22]; const float* hb1 = (const float*)d_in[23];
    const float* hw2 = (const float*)d_in[24]; const float* hb2 = (const float*)d_in[25];
    float* out = (float*)d_out;

    // ---- workspace layout ----
    char* base = (char*)d_ws;
    unsigned short* fused_b = (unsigned short*)base;                       // M*512 bf16 = 67 MB
    float4* fmap4 = (float4*)(fused_b + (size_t)M_TOT*512);                // 16*3136 float4
    float* g3   = (float*)(fmap4 + (size_t)16*3136);                       // 16*16*784 (OUT of alias region)
    float* g4o  = g3 + (size_t)16*16*784;                                  // 16*196*32 (OUT of alias region)
    float* gc   = g4o + (size_t)16*32*196;                                 // 1024
    float* hgc  = gc + 1024;                                               // 16*512
    unsigned short* blw1 = (unsigned short*)(hgc + 16*512);                // 256*64
    unsigned short* blw2 = blw1 + 256*64;                                  // 256*256
    unsigned short* bhw1 = blw2 + 256*256;                                 // 512*576 (col-permuted)
    // conv temps f1,f2,g1,g2 alias inside fused region (dead before k4 writes fused):
    float* ct = (float*)base;
    float* f1 = ct;
    float* f2 = f1 + (size_t)16*16*112*112;
    float* g1 = f2 + (size_t)16*32*56*56;
    float* g2 = g1 + (size_t)16*4*112*112;

    cvtall_k<<<1472, 256, 0, stream>>>(lw1, lw2, hw1, blw1, blw2, bhw1, out, hb2, gc);
    conv_dual_k<<<dim3(7,7,16), 256, 0, stream>>>(images, pw1, pb1, gw1, gb1, f1, g1);
    conv_pg2_k<<<dim3(4,4,48), 256, 0, stream>>>(f1, pw2, pb2, f2, g1, gw2, gb2, g2);
    conv_pg3_k<<<dim3(13,1,32), 256, 0, stream>>>(f2, pw3, pb3, fmap4, g2, gw3, gb3, g3);
    // K4: g4 + patch fill (fill depends only on pg3; runs at full-machine parallelism)
    k4_k<<<392 + 16384, 256, 0, stream>>>(g3, gw4, gb4, g4o, fmap4, points, fused_b);
    g5_k<<<196, 256, 0, stream>>>(g4o, gw5, gb5, gc);   // includes avgpool via atomics
    hgc_k<<<32, 256, 0, stream>>>(gc, hw1, hb1, hgc);   // fold gc into head bias (fp32)
    // mlp12: pure GEMM now (pe shared in LDS), writes fused cols 0..255
    mlp12_k<<<M_TOT/128, 512, 0, stream>>>(points, blw1, lb1, blw2, lb2, fused_b);
    gemm_hd_k<<<dim3(M_TOT/64, 2), 256, 0, stream>>>(fused_b, bhw1, hgc, hw2, out);
}